// Round 1
// baseline (15.213 us; speedup 1.0000x reference)
//
#include <hip/hip_runtime.h>

// MemristorConv1d: (B=4, F=512, T=1000), K=31, 3 bit-planes.
// out[b,f,t] = ( sum_p BW[p] * ADC( sum_k d[b,f,t+k-15] * (r_pos[p,f,k]-r_neg[p,f,k]) ) ) * 0.02 + bias[f]
// d(v)  = v * (Phrs(v^2) - Plrs(v^2)),  v = DAC(in * 0.25)

#define KW 31
#define PADW 15
#define TT 1000
#define FF 512
#define NP 3
#define BLOCK 256

__global__ __launch_bounds__(BLOCK) void memristor_conv1d_kernel(
    const float* __restrict__ inputs,   // (B,F,T)
    const float* __restrict__ r_pos,    // (NP,F,K)
    const float* __restrict__ r_neg,    // (NP,F,K)
    const float* __restrict__ bias,     // (F)
    float* __restrict__ out)            // (B,F,T)
{
    const int bf  = blockIdx.x;         // b*F + f
    const int f   = bf & (FF - 1);
    const int tid = threadIdx.x;

    __shared__ float d_lds[TT + 2 * PADW];   // 1030 floats
    __shared__ float w_lds[NP][KW];          // 93 floats

    // Stage weights (r_pos - r_neg) for this feature.
    if (tid < NP * KW) {
        const int p = tid / KW;
        const int k = tid - p * KW;
        const size_t off = ((size_t)p * FF + f) * KW + k;
        w_lds[p][k] = r_pos[off] - r_neg[off];
    }

    // Stage input row -> DAC -> polynomial "diff" factor, with zero padding.
    const float* in_row = inputs + (size_t)bf * TT;
    for (int t = tid; t < TT + 2 * PADW; t += BLOCK) {
        float dv = 0.0f;
        const int ti = t - PADW;
        if (ti >= 0 && ti < TT) {
            // DAC: clip, quantize to 127 levels, scale to +-0.6 V
            float x = in_row[ti] * 0.25f;
            float v = fminf(fmaxf(x, -1.0f), 1.0f);
            v = rintf(v * 127.0f) / 127.0f * 0.6f;   // rintf == round-half-even == jnp.round
            // diff = v * (Phrs(v2) - Plrs(v2))
            const float v2 = v * v;
            const float ph = 2e-06f + v2 * (5e-08f + v2 * 1e-09f);
            const float pl = 3e-04f + v2 * (4e-06f + v2 * 2e-07f);
            dv = v * (ph - pl);
        }
        d_lds[t] = dv;
    }
    __syncthreads();

    const float bv = bias[f];
    float* out_row = out + (size_t)bf * TT;

    for (int t = tid; t < TT; t += BLOCK) {
        float c0 = 0.0f, c1 = 0.0f, c2 = 0.0f;
        #pragma unroll
        for (int k = 0; k < KW; ++k) {
            const float dv = d_lds[t + k];
            c0 = fmaf(dv, w_lds[0][k], c0);
            c1 = fmaf(dv, w_lds[1][k], c1);
            c2 = fmaf(dv, w_lds[2][k], c2);
        }
        // ADC: round(i*5000/2^-8)*2^-8, clip to +-16.
        // c * (5000*256) rounds identically to (c*5000)*256 (exact pow2 scale).
        float a0 = fminf(fmaxf(rintf(c0 * 1280000.0f) * (1.0f / 256.0f), -16.0f), 16.0f);
        float a1 = fminf(fmaxf(rintf(c1 * 1280000.0f) * (1.0f / 256.0f), -16.0f), 16.0f);
        float a2 = fminf(fmaxf(rintf(c2 * 1280000.0f) * (1.0f / 256.0f), -16.0f), 16.0f);
        out_row[t] = (a0 * 4.0f + a1 * 2.0f + a2) * 0.02f + bv;
    }
}

extern "C" void kernel_launch(void* const* d_in, const int* in_sizes, int n_in,
                              void* d_out, int out_size, void* d_ws, size_t ws_size,
                              hipStream_t stream) {
    const float* inputs = (const float*)d_in[0];   // (4,512,1000)
    const float* r_pos  = (const float*)d_in[1];   // (3,512,31)
    const float* r_neg  = (const float*)d_in[2];   // (3,512,31)
    const float* bias   = (const float*)d_in[3];   // (512)
    float* out = (float*)d_out;                    // (4,512,1000)

    const int B = in_sizes[0] / (FF * TT);         // 4
    dim3 grid(B * FF);
    dim3 block(BLOCK);
    memristor_conv1d_kernel<<<grid, block, 0, stream>>>(inputs, r_pos, r_neg, bias, out);
}